// Round 1
// baseline (1107.044 us; speedup 1.0000x reference)
//
#include <hip/hip_runtime.h>

// LSTM: I=16, H=32, B=8192, T=512. fp32 in/out.
// Thread = (row, k): owns h[row][k], c[row][k]; computes gates j = k+32g.
// Weights register-cached (192 VGPRs/thread); h shared via double-buffered LDS
// (1 barrier/step); x staged in 32-step LDS chunks with register prefetch.

constexpr int ISZ = 16;    // input size
constexpr int HSZ = 32;    // hidden size
constexpr int TT  = 512;   // timesteps
constexpr int BB  = 8192;  // batch
constexpr int RPB = 8;     // rows per block (256 threads / 32)
constexpr int TCH = 32;    // timesteps per x-chunk staged in LDS
constexpr int NCH = TT / TCH;
constexpr int F4_PER_ROW = TT * ISZ / 4;          // 2048 float4 per row
constexpr int F4_PER_CHUNK_ROW = TCH * ISZ / 4;   // 128

__device__ __forceinline__ float frcp(float x) { return __builtin_amdgcn_rcpf(x); }
__device__ __forceinline__ float fsig(float x) { return frcp(1.0f + __expf(-x)); }
__device__ __forceinline__ float ftanh(float x) {
  // tanh(x) = 1 - 2/(e^{2x}+1); saturates correctly for |x| large.
  return 1.0f - 2.0f * frcp(1.0f + __expf(2.0f * x));
}

__global__ __launch_bounds__(256, 2) void lstm_kernel(
    const float* __restrict__ x, const float* __restrict__ W_ih,
    const float* __restrict__ W_hh, const float* __restrict__ b_ih,
    const float* __restrict__ b_hh, const float* __restrict__ W_fc,
    const float* __restrict__ b_fc, float* __restrict__ out) {
  __shared__ float xs[TCH * RPB * ISZ];   // [tch][r][i]
  __shared__ float hsh[2][RPB * HSZ];     // double-buffered h per row

  const int tid = threadIdx.x;
  const int r = tid >> 5;    // row within block
  const int k = tid & 31;    // hidden unit
  const int row0 = blockIdx.x * RPB;
  const int row = row0 + r;

  // ---- Register-cache weights for this thread's 4 gate rows (j = k+32g) ----
  float wih[4][ISZ];
  float whh[4][HSZ];
  float bias[4];
#pragma unroll
  for (int g = 0; g < 4; ++g) {
    const int j = k + 32 * g;
    const float4* wp = (const float4*)(W_ih + j * ISZ);
#pragma unroll
    for (int q = 0; q < ISZ / 4; ++q) {
      float4 v = wp[q];
      wih[g][4 * q + 0] = v.x; wih[g][4 * q + 1] = v.y;
      wih[g][4 * q + 2] = v.z; wih[g][4 * q + 3] = v.w;
    }
    const float4* hp = (const float4*)(W_hh + j * HSZ);
#pragma unroll
    for (int q = 0; q < HSZ / 4; ++q) {
      float4 v = hp[q];
      whh[g][4 * q + 0] = v.x; whh[g][4 * q + 1] = v.y;
      whh[g][4 * q + 2] = v.z; whh[g][4 * q + 3] = v.w;
    }
    bias[g] = b_ih[j] + b_hh[j];
  }

  // init h buffer 0 (RPB*HSZ == 256 == blockDim)
  hsh[0][tid] = 0.0f;

  float h = 0.0f, c = 0.0f;
  int p = 0;

  const float4* x4 = (const float4*)x;

  // ---- Prefetch chunk 0 into registers ----
  float4 pre[4];
#pragma unroll
  for (int it = 0; it < 4; ++it) {
    const int f = it * 256 + tid;
    const int rr = f >> 7;        // which row (128 f4 per row-chunk)
    const int rem = f & 127;
    pre[it] = x4[(size_t)(row0 + rr) * F4_PER_ROW + rem];
  }

  for (int ch = 0; ch < NCH; ++ch) {
    // write prefetched chunk into LDS as [tch][r][i]
#pragma unroll
    for (int it = 0; it < 4; ++it) {
      const int f = it * 256 + tid;
      const int rr = f >> 7;
      const int rem = f & 127;
      const int tch = rem >> 2, i4 = rem & 3;
      ((float4*)xs)[tch * (RPB * ISZ / 4) + rr * (ISZ / 4) + i4] = pre[it];
    }
    // prefetch next chunk (hidden under this chunk's 32 steps of compute)
    const int nch = (ch + 1 < NCH) ? ch + 1 : ch;
#pragma unroll
    for (int it = 0; it < 4; ++it) {
      const int f = it * 256 + tid;
      const int rr = f >> 7;
      const int rem = f & 127;
      pre[it] = x4[(size_t)(row0 + rr) * F4_PER_ROW + nch * F4_PER_CHUNK_ROW + rem];
    }
    __syncthreads();

    for (int tl = 0; tl < TCH; ++tl) {
      float a0 = bias[0], a1 = bias[1], a2 = bias[2], a3 = bias[3];

      // x contribution: 64 FMAs
      float xv[ISZ];
      const float4* xr = (const float4*)(xs + tl * (RPB * ISZ) + r * ISZ);
#pragma unroll
      for (int q = 0; q < ISZ / 4; ++q) {
        float4 v = xr[q];
        xv[4 * q + 0] = v.x; xv[4 * q + 1] = v.y;
        xv[4 * q + 2] = v.z; xv[4 * q + 3] = v.w;
      }
#pragma unroll
      for (int i = 0; i < ISZ; ++i) {
        a0 += xv[i] * wih[0][i]; a1 += xv[i] * wih[1][i];
        a2 += xv[i] * wih[2][i]; a3 += xv[i] * wih[3][i];
      }

      // h contribution: 128 FMAs
      float hv[HSZ];
      const float4* hr = (const float4*)(hsh[p] + r * HSZ);
#pragma unroll
      for (int q = 0; q < HSZ / 4; ++q) {
        float4 v = hr[q];
        hv[4 * q + 0] = v.x; hv[4 * q + 1] = v.y;
        hv[4 * q + 2] = v.z; hv[4 * q + 3] = v.w;
      }
#pragma unroll
      for (int kk = 0; kk < HSZ; ++kk) {
        a0 += hv[kk] * whh[0][kk]; a1 += hv[kk] * whh[1][kk];
        a2 += hv[kk] * whh[2][kk]; a3 += hv[kk] * whh[3][kk];
      }

      // cell update (gate order i,f,g,o)
      const float ig = fsig(a0);
      const float fg = fsig(a1);
      const float gg = ftanh(a2);
      const float og = fsig(a3);
      c = fg * c + ig * gg;
      h = og * ftanh(c);

      hsh[p ^ 1][r * HSZ + k] = h;
      __syncthreads();
      p ^= 1;
    }
  }

  // ---- Output: out[row] = sum_k h[k]*W_fc[k] + b_fc ----
  float v = h * W_fc[k];
#pragma unroll
  for (int off = 16; off > 0; off >>= 1) v += __shfl_down(v, off, 32);
  if (k == 0) out[row] = v + b_fc[0];
}

extern "C" void kernel_launch(void* const* d_in, const int* in_sizes, int n_in,
                              void* d_out, int out_size, void* d_ws, size_t ws_size,
                              hipStream_t stream) {
  const float* x    = (const float*)d_in[0];
  const float* W_ih = (const float*)d_in[1];
  const float* W_hh = (const float*)d_in[2];
  const float* b_ih = (const float*)d_in[3];
  const float* b_hh = (const float*)d_in[4];
  const float* W_fc = (const float*)d_in[5];
  const float* b_fc = (const float*)d_in[6];
  float* out = (float*)d_out;

  dim3 grid(BB / RPB);   // 1024 blocks
  dim3 block(256);
  lstm_kernel<<<grid, block, 0, stream>>>(x, W_ih, W_hh, b_ih, b_hh, W_fc, b_fc, out);
}

// Round 2
// 970.362 us; speedup vs baseline: 1.1409x; 1.1409x over previous
//
#include <hip/hip_runtime.h>

// LSTM I=16, H=32, B=8192, T=512, fp32.
// Wave = one batch row (64 lanes). Lane l owns gate rows j=l and j=l+64
// (l<32: i,g for unit l; l>=32: f,o for unit l-32) -> 96 weight floats/lane,
// held as 48 v2f pairs feeding v_pk_fma_f32. h double-buffered in LDS
// (intra-wave in-order LDS pipe => NO barriers anywhere). Gate exchange via
// __shfl_xor(.,32). x staged per-row in double-buffered LDS chunks with
// register prefetch (2 float4/lane per 32 steps).

typedef float v2f __attribute__((ext_vector_type(2)));

constexpr int ISZ = 16, HSZ = 32, TT = 512, BB = 8192;
constexpr int RPB = 4;              // rows per block (256 threads / 64)
constexpr int TCH = 32;             // timesteps per staged x chunk
constexpr int NCH = TT / TCH;       // 16
constexpr int F4_PER_ROW = TT * ISZ / 4;        // 2048
constexpr int F4_PER_CHUNK = TCH * ISZ / 4;     // 128

__device__ __forceinline__ float fsig(float x) {
  return __builtin_amdgcn_rcpf(1.0f + __expf(-x));
}
__device__ __forceinline__ v2f pf(v2f a, v2f b, v2f c) {
  return __builtin_elementwise_fma(a, b, c);
}
__device__ __forceinline__ v2f lo2(float4 v) { return (v2f){v.x, v.y}; }
__device__ __forceinline__ v2f hi2(float4 v) { return (v2f){v.z, v.w}; }

__global__ __launch_bounds__(256, 3) void lstm_kernel(
    const float* __restrict__ x, const float* __restrict__ W_ih,
    const float* __restrict__ W_hh, const float* __restrict__ b_ih,
    const float* __restrict__ b_hh, const float* __restrict__ W_fc,
    const float* __restrict__ b_fc, float* __restrict__ out) {
  __shared__ float xs[RPB][2][TCH * ISZ];  // 16 KB
  __shared__ float hb[RPB][2][HSZ];        // 1 KB

  const int tid = threadIdx.x;
  const int r = tid >> 6;     // row within block
  const int l = tid & 63;     // lane within row-wave
  const int row = blockIdx.x * RPB + r;
  const bool lo = (l < 32);
  const int jA = l;           // gate row A: i (l<32) or f (l>=32)
  const int jB = l + 64;      // gate row B: g (l<32) or o (l>=32)

  // ---- weights: 48 v2f pairs per lane ----
  v2f wihA[8], wihB[8], whhA[16], whhB[16];
  {
    const float4* pa = (const float4*)(W_ih + jA * ISZ);
    const float4* pb = (const float4*)(W_ih + jB * ISZ);
#pragma unroll
    for (int q = 0; q < 4; ++q) {
      float4 va = pa[q], vb = pb[q];
      wihA[2 * q] = lo2(va); wihA[2 * q + 1] = hi2(va);
      wihB[2 * q] = lo2(vb); wihB[2 * q + 1] = hi2(vb);
    }
    const float4* ha = (const float4*)(W_hh + jA * HSZ);
    const float4* hbp = (const float4*)(W_hh + jB * HSZ);
#pragma unroll
    for (int q = 0; q < 8; ++q) {
      float4 va = ha[q], vb = hbp[q];
      whhA[2 * q] = lo2(va); whhA[2 * q + 1] = hi2(va);
      whhB[2 * q] = lo2(vb); whhB[2 * q + 1] = hi2(vb);
    }
  }
  const float bA = b_ih[jA] + b_hh[jA];
  const float bB = b_ih[jB] + b_hh[jB];

  // init h buffer 0 for this row
  if (lo) hb[r][0][l] = 0.0f;

  float c = 0.0f, hcur = 0.0f;
  int hp = 0, bufx = 0;

  const float4* x4 = (const float4*)x;
  const size_t xbase = (size_t)row * F4_PER_ROW;

  // prefetch chunk 0 (2 float4 per lane covers 128 f4 = one row-chunk)
  float4 p0 = x4[xbase + 2 * l];
  float4 p1 = x4[xbase + 2 * l + 1];

  for (int ch = 0; ch < NCH; ++ch) {
    // commit prefetched chunk into LDS (waits vmcnt; hidden by prev chunk)
    float4* xw = (float4*)xs[r][bufx];
    xw[2 * l] = p0;
    xw[2 * l + 1] = p1;
    // prefetch next chunk
    const int nc = (ch + 1 < NCH) ? ch + 1 : ch;
    p0 = x4[xbase + nc * F4_PER_CHUNK + 2 * l];
    p1 = x4[xbase + nc * F4_PER_CHUNK + 2 * l + 1];

    const float4* xrow = (const float4*)xs[r][bufx];
#pragma unroll 4
    for (int tl = 0; tl < TCH; ++tl) {
      v2f accA = (v2f){bA, 0.0f};
      v2f accB = (v2f){bB, 0.0f};

      // x contribution: 16 MACs per gate (8 pk_fma each)
#pragma unroll
      for (int q = 0; q < 4; ++q) {
        float4 xv = xrow[tl * 4 + q];       // wave-broadcast read
        v2f x0 = lo2(xv), x1 = hi2(xv);
        accA = pf(x0, wihA[2 * q], accA);
        accA = pf(x1, wihA[2 * q + 1], accA);
        accB = pf(x0, wihB[2 * q], accB);
        accB = pf(x1, wihB[2 * q + 1], accB);
      }
      // h contribution: 32 MACs per gate (16 pk_fma each)
      const float4* hr = (const float4*)hb[r][hp];
#pragma unroll
      for (int q = 0; q < 8; ++q) {
        float4 hv = hr[q];                  // wave-broadcast read
        v2f h0 = lo2(hv), h1 = hi2(hv);
        accA = pf(h0, whhA[2 * q], accA);
        accA = pf(h1, whhA[2 * q + 1], accA);
        accB = pf(h0, whhB[2 * q], accB);
        accB = pf(h1, whhB[2 * q + 1], accB);
      }
      const float gA = accA.x + accA.y;     // i (lo) or f (hi)
      const float gB0 = accB.x + accB.y;    // g (lo) or o (hi)

      const float sA = fsig(gA);
      // gate B: tanh for g (lo) via 2*sig(2x)-1, sigmoid for o (hi)
      const float aB2 = lo ? (gB0 + gB0) : gB0;
      const float s = fsig(aB2);
      const float gB = lo ? (2.0f * s - 1.0f) : s;

      // exchange: lane k (<32) gets f,o from lane k+32
      const float fO = __shfl_xor(sA, 32, 64);
      const float oO = __shfl_xor(gB, 32, 64);

      // state update (valid on lanes <32; upper lanes compute garbage)
      c = fO * c + sA * gB;                 // sig(f)*c + sig(i)*tanh(g)
      const float th = 2.0f * fsig(c + c) - 1.0f;  // tanh(c)
      hcur = oO * th;                       // sig(o)*tanh(c)

      if (lo) hb[r][hp ^ 1][l] = hcur;
      hp ^= 1;
    }
    bufx ^= 1;
  }

  // out[row] = sum_k h[k]*W_fc[k] + b_fc
  float v = lo ? hcur * W_fc[lo ? l : 0] : 0.0f;
#pragma unroll
  for (int off = 16; off > 0; off >>= 1) v += __shfl_down(v, off, 64);
  if (l == 0) out[row] = v + b_fc[0];
}

extern "C" void kernel_launch(void* const* d_in, const int* in_sizes, int n_in,
                              void* d_out, int out_size, void* d_ws, size_t ws_size,
                              hipStream_t stream) {
  const float* x    = (const float*)d_in[0];
  const float* W_ih = (const float*)d_in[1];
  const float* W_hh = (const float*)d_in[2];
  const float* b_ih = (const float*)d_in[3];
  const float* b_hh = (const float*)d_in[4];
  const float* W_fc = (const float*)d_in[5];
  const float* b_fc = (const float*)d_in[6];
  float* out = (float*)d_out;

  dim3 grid(BB / RPB);   // 2048 blocks
  dim3 block(256);
  lstm_kernel<<<grid, block, 0, stream>>>(x, W_ih, W_hh, b_ih, b_hh, W_fc, b_fc, out);
}